// Round 8
// baseline (425.822 us; speedup 1.0000x reference)
//
#include <hip/hip_runtime.h>
#include <hip/hip_cooperative_groups.h>

namespace cg = cooperative_groups;

#define NJ 1024
#define DETECT 0.5f
#define RESCUE 0.4975f   // 0.5 minus u8 error bound (0.00196), with margin

__device__ __forceinline__ float sample_t(int s) {
    // jnp.linspace(0,1,64) fp32 semantics (endpoint exactly 1.0)
    return (s == 63) ? 1.0f : (float)s * (1.0f / 63.0f);
}

// Exact fp32 recompute for pair (a -> weight t, b -> weight 1-t), reference op order.
__device__ __forceinline__ void exact_pair(const float2 ja, const float2 jb,
                                           const float* __restrict__ heat,
                                           float& mean_o, float& min_o)
{
    float acc = 0.0f;
    float mn  = __builtin_inff();
    for (int s = 0; s < 64; ++s) {
        const float t  = sample_t(s);
        const float om = 1.0f - t;
        float ch = __fadd_rn(__fmul_rn(ja.x, t), __fmul_rn(jb.x, om));
        float cw = __fadd_rn(__fmul_rn(ja.y, t), __fmul_rn(jb.y, om));
        ch = fminf(fmaxf(ch, 0.0f), 1023.0f);
        cw = fminf(fmaxf(cw, 0.0f), 1023.0f);
        const float hf = floorf(ch), hc = ceilf(ch);
        const float wf = floorf(cw), wc = ceilf(cw);
        const int hfi = (int)hf, hci = (int)hc;
        const int wfi = (int)wf, wci = (int)wc;
        const float a00 = heat[(hfi << 10) + wfi];
        const float a01 = heat[(hfi << 10) + wci];
        const float a10 = heat[(hci << 10) + wfi];
        const float a11 = heat[(hci << 10) + wci];
        const float t1 = __fmul_rn(__fmul_rn(a00, __fsub_rn(hc, ch)), __fsub_rn(wc, cw));
        const float t2 = __fmul_rn(__fmul_rn(a01, __fsub_rn(hc, ch)), __fsub_rn(cw, wf));
        const float t3 = __fmul_rn(__fmul_rn(a10, __fsub_rn(ch, hf)), __fsub_rn(wc, cw));
        const float t4 = __fmul_rn(__fmul_rn(a11, __fsub_rn(ch, hf)), __fsub_rn(cw, wf));
        const float feat = __fadd_rn(__fadd_rn(__fadd_rn(t1, t2), t3), t4);
        acc += feat;
        mn = fminf(mn, feat);
    }
    mean_o = acc * (1.0f / 64.0f);
    min_o  = mn;
}

// Pack 4 consecutive cells: packed[h][w] = 2x2 u8 corner block in one dword.
__device__ __forceinline__ void pack4(const float* __restrict__ heat,
                                      uint4* __restrict__ packed4, int idx)
{
    const int h = idx >> 8;                           // row
    const int w4 = (idx & 255) << 2;                  // first of 4 cells
    const int hn = (h < 1023) ? h + 1 : 1023;
    const float* r0 = heat + (h  << 10);
    const float* r1 = heat + (hn << 10);
    const float4 a = *(const float4*)(r0 + w4);
    const float4 b = *(const float4*)(r1 + w4);
    const int wnext = (w4 + 4 <= 1023) ? w4 + 4 : 1023;
    const float a4 = r0[wnext];
    const float b4 = r1[wnext];

    const float av[5] = {a.x, a.y, a.z, a.w, a4};
    const float bv[5] = {b.x, b.y, b.z, b.w, b4};
    unsigned int out[4];
    #pragma unroll
    for (int u = 0; u < 4; ++u) {
        const unsigned int c0 = (unsigned int)__float2int_rn(av[u]     * 255.0f);
        const unsigned int c1 = (unsigned int)__float2int_rn(av[u + 1] * 255.0f);
        const unsigned int c2 = (unsigned int)__float2int_rn(bv[u]     * 255.0f);
        const unsigned int c3 = (unsigned int)__float2int_rn(bv[u + 1] * 255.0f);
        out[u] = c0 | (c1 << 8) | (c2 << 16) | (c3 << 24);
    }
    packed4[idx] = make_uint4(out[0], out[1], out[2], out[3]);
}

// One pair (r, c) with c in [1,512]; j = (r+c) mod 1024. u8 fast path + exact
// rescue. Writes BOTH orientations (scattered p2 measured ~equal to
// single-write + separate mirror kernel, and saves a dispatch).
__device__ __forceinline__ void do_pair(const float* __restrict__ junc,
                                        const float* __restrict__ heat,
                                        const unsigned int* __restrict__ packed,
                                        float* __restrict__ line_out,
                                        float* __restrict__ mean_out,
                                        int r, int c)
{
    const int j = (r + c) & 1023;
    const float2 jr  = ((const float2*)junc)[r];
    const float2 jjc = ((const float2*)junc)[j];

    float acc = 0.0f;           // in u8 counts (x255)
    float mn  = __builtin_inff();

    #pragma unroll
    for (int s0 = 0; s0 < 64; s0 += 16) {
        float chv[16], cwv[16];
        unsigned int cv[16];
        #pragma unroll
        for (int u = 0; u < 16; ++u) {
            const int s = s0 + u;
            const float t  = sample_t(s);
            const float om = 1.0f - t;
            // Reference op order: ji*t + jj*(1-t), contraction-proof.
            float ch = __fadd_rn(__fmul_rn(jr.x, t), __fmul_rn(jjc.x, om));
            float cw = __fadd_rn(__fmul_rn(jr.y, t), __fmul_rn(jjc.y, om));
            ch = fminf(fmaxf(ch, 0.0f), 1023.0f);
            cw = fminf(fmaxf(cw, 0.0f), 1023.0f);
            chv[u] = ch;
            cwv[u] = cw;
            const int hfi = (int)ch;   // trunc == floor for non-negative
            const int wfi = (int)cw;
            cv[u] = packed[(hfi << 10) + wfi];
        }
        #pragma unroll
        for (int u = 0; u < 16; ++u) {
            const float ch = chv[u], cw = cwv[u];
            const float hf = floorf(ch), hc = ceilf(ch);
            const float wf = floorf(cw), wc = ceilf(cw);
            const float wh0 = hc - ch, wh1 = ch - hf;
            const float ww0 = wc - cw, ww1 = cw - wf;
            const unsigned int cc = cv[u];
            const float a00 = (float)(cc & 0xffu);
            const float a01 = (float)((cc >> 8) & 0xffu);
            const float a10 = (float)((cc >> 16) & 0xffu);
            const float a11 = (float)(cc >> 24);
            const float feat = a00 * (wh0 * ww0) + a01 * (wh0 * ww1)
                             + a10 * (wh1 * ww0) + a11 * (wh1 * ww1);
            acc += feat;
            mn = fminf(mn, feat);
        }
    }

    float mean = acc * (1.0f / (255.0f * 64.0f));
    const float mns = mn * (1.0f / 255.0f);

    // Conservative candidate test: exact detection implies u8 min/mean > RESCUE.
    bool det = false;
    if ((mns > RESCUE) && (mean > RESCUE)) {
        float mn2;
        exact_pair(jr, jjc, heat, mean, mn2);
        det = (mean > DETECT) && (mn2 > DETECT);
    }

    const float lv = det ? 1.0f : 0.0f;
    const int p1 = (r << 10) + j;
    const int p2 = (j << 10) + r;
    mean_out[p1] = mean;     // coalesced
    mean_out[p2] = mean;     // scattered mirror (symmetric sample set)
    line_out[p1] = lv;
    line_out[p2] = lv;
}

// Diagonal cell (r,r): exact mean, line=0 (strict upper-tri excludes diagonal).
__device__ __forceinline__ void do_diag(const float* __restrict__ junc,
                                        const float* __restrict__ heat,
                                        float* __restrict__ line_out,
                                        float* __restrict__ mean_out, int r)
{
    const float2 jr = ((const float2*)junc)[r];
    float mean, mnv;
    exact_pair(jr, jr, heat, mean, mnv);
    const int p = (r << 10) + r;
    mean_out[p] = mean;
    line_out[p] = 0.0f;
}

// Single cooperative kernel: 1024 blocks x 256 threads (4 blocks/CU).
// Phase 1: pack (4 cells/thread) + diagonal (threads < 1024, reads heat only).
// Phase 2 (after grid sync): 2 band pairs per thread, dual-orientation writes.
__global__ __launch_bounds__(256, 4) void sold2_fused_kernel(
    const float* __restrict__ junc, const float* __restrict__ heat,
    unsigned int* __restrict__ packed,
    float* __restrict__ line_out, float* __restrict__ mean_out)
{
    const int q = blockIdx.x * 256 + threadIdx.x;   // 0 .. 262143

    pack4(heat, (uint4*)packed, q);
    if (q < NJ) do_diag(junc, heat, line_out, mean_out, q);

    __threadfence();              // device-scope release (cross-XCD visibility)
    cg::this_grid().sync();       // includes acquire on the consumer side

    #pragma unroll 1
    for (int half = 0; half < 2; ++half) {
        const int r = (q >> 9) | (half << 9);   // [0,512) then [512,1024)
        const int c = (q & 511) + 1;            // [1,512]
        do_pair(junc, heat, packed, line_out, mean_out, r, c);
    }
}

// ---- Non-cooperative fallback (2 dispatches), same numerics ----
__global__ __launch_bounds__(256) void pack_diag_kernel(
    const float* __restrict__ heat, uint4* __restrict__ packed4,
    const float* __restrict__ junc,
    float* __restrict__ line_out, float* __restrict__ mean_out)
{
    const int q = blockIdx.x * 256 + threadIdx.x;
    pack4(heat, packed4, q);
    if (q < NJ) do_diag(junc, heat, line_out, mean_out, q);
}

__global__ __launch_bounds__(256) void band_kernel(
    const float* __restrict__ junc, const float* __restrict__ heat,
    const unsigned int* __restrict__ packed,
    float* __restrict__ line_out, float* __restrict__ mean_out)
{
    const int q = blockIdx.x * 256 + threadIdx.x;   // 0 .. 524287
    do_pair(junc, heat, packed, line_out, mean_out, q >> 9, (q & 511) + 1);
}

extern "C" void kernel_launch(void* const* d_in, const int* in_sizes, int n_in,
                              void* d_out, int out_size, void* d_ws, size_t ws_size,
                              hipStream_t stream) {
    const float* junc = (const float*)d_in[0];   // [1024,2] float32
    const float* heat = (const float*)d_in[1];   // [1024,1024] float32
    float* line_out = (float*)d_out;
    float* mean_out = line_out + NJ * NJ;
    unsigned int* packed = (unsigned int*)d_ws;  // 4 MB scratch

    void* args[] = {(void*)&junc, (void*)&heat, (void*)&packed,
                    (void*)&line_out, (void*)&mean_out};
    hipError_t err = hipLaunchCooperativeKernel(
        (const void*)sold2_fused_kernel, dim3(1024), dim3(256), args, 0, stream);

    if (err != hipSuccess) {
        // Fallback: same work in 2 plain dispatches (deterministic every call).
        pack_diag_kernel<<<1024, 256, 0, stream>>>(heat, (uint4*)packed, junc,
                                                   line_out, mean_out);
        band_kernel<<<2048, 256, 0, stream>>>(junc, heat, packed,
                                              line_out, mean_out);
    }
}

// Round 9
// 186.146 us; speedup vs baseline: 2.2876x; 2.2876x over previous
//
#include <hip/hip_runtime.h>

#define NJ 1024
#define DETECT 0.5f
#define RESCUE 0.4975f   // 0.5 minus u8 error bound (0.00196), with margin

__device__ __forceinline__ float sample_t(int s) {
    // jnp.linspace(0,1,64) fp32 semantics (endpoint exactly 1.0)
    return (s == 63) ? 1.0f : (float)s * (1.0f / 63.0f);
}

// Exact fp32 recompute for pair (a -> weight t, b -> weight 1-t), reference op order.
__device__ __forceinline__ void exact_pair(const float2 ja, const float2 jb,
                                           const float* __restrict__ heat,
                                           float& mean_o, float& min_o)
{
    float acc = 0.0f;
    float mn  = __builtin_inff();
    for (int s = 0; s < 64; ++s) {
        const float t  = sample_t(s);
        const float om = 1.0f - t;
        float ch = __fadd_rn(__fmul_rn(ja.x, t), __fmul_rn(jb.x, om));
        float cw = __fadd_rn(__fmul_rn(ja.y, t), __fmul_rn(jb.y, om));
        ch = fminf(fmaxf(ch, 0.0f), 1023.0f);
        cw = fminf(fmaxf(cw, 0.0f), 1023.0f);
        const float hf = floorf(ch), hc = ceilf(ch);
        const float wf = floorf(cw), wc = ceilf(cw);
        const int hfi = (int)hf, hci = (int)hc;
        const int wfi = (int)wf, wci = (int)wc;
        const float a00 = heat[(hfi << 10) + wfi];
        const float a01 = heat[(hfi << 10) + wci];
        const float a10 = heat[(hci << 10) + wfi];
        const float a11 = heat[(hci << 10) + wci];
        const float t1 = __fmul_rn(__fmul_rn(a00, __fsub_rn(hc, ch)), __fsub_rn(wc, cw));
        const float t2 = __fmul_rn(__fmul_rn(a01, __fsub_rn(hc, ch)), __fsub_rn(cw, wf));
        const float t3 = __fmul_rn(__fmul_rn(a10, __fsub_rn(ch, hf)), __fsub_rn(wc, cw));
        const float t4 = __fmul_rn(__fmul_rn(a11, __fsub_rn(ch, hf)), __fsub_rn(cw, wf));
        const float feat = __fadd_rn(__fadd_rn(__fadd_rn(t1, t2), t3), t4);
        acc += feat;
        mn = fminf(mn, feat);
    }
    mean_o = acc * (1.0f / 64.0f);
    min_o  = mn;
}

// Stage: packed[h][w] = 2x2 corner block as 4x u8 in one dword (4 MB, L2-resident).
// Vectorized: each thread packs 4 consecutive cells. nt store: packed is written
// once, read by the next kernel from L2 via fresh fetch either way.
__global__ __launch_bounds__(256) void pack_kernel(
    const float* __restrict__ heat, uint4* __restrict__ packed4)
{
    const int idx = blockIdx.x * 256 + threadIdx.x;   // 0 .. 256K-1
    const int h = idx >> 8;                           // row
    const int w4 = (idx & 255) << 2;                  // first of 4 cells
    const int hn = (h < 1023) ? h + 1 : 1023;
    const float* r0 = heat + (h  << 10);
    const float* r1 = heat + (hn << 10);
    const float4 a = *(const float4*)(r0 + w4);
    const float4 b = *(const float4*)(r1 + w4);
    const int wnext = (w4 + 4 <= 1023) ? w4 + 4 : 1023;
    const float a4 = r0[wnext];
    const float b4 = r1[wnext];

    const float av[5] = {a.x, a.y, a.z, a.w, a4};
    const float bv[5] = {b.x, b.y, b.z, b.w, b4};
    unsigned int out[4];
    #pragma unroll
    for (int u = 0; u < 4; ++u) {
        const unsigned int c0 = (unsigned int)__float2int_rn(av[u]     * 255.0f);
        const unsigned int c1 = (unsigned int)__float2int_rn(av[u + 1] * 255.0f);
        const unsigned int c2 = (unsigned int)__float2int_rn(bv[u]     * 255.0f);
        const unsigned int c3 = (unsigned int)__float2int_rn(bv[u + 1] * 255.0f);
        out[u] = c0 | (c1 << 8) | (c2 << 16) | (c3 << 24);
    }
    packed4[idx] = make_uint4(out[0], out[1], out[2], out[3]);
}

// One thread per pair-orientation in the band c in [0,512];
// q = r*513 + c ; j = (r+c) mod 1024. Writes ONLY its own cell (coalesced, nt).
// The complement band (c in [513,1023]) is filled by mirror_kernel.
__global__ __launch_bounds__(256) void sold2_thread_kernel(
    const float* __restrict__ junc,          // [N,2] (h,w)
    const float* __restrict__ heat,          // [H,W] fp32 (exact rescue path)
    const unsigned int* __restrict__ packed, // [H,W] u8x4 corner blocks
    float* __restrict__ line_out,            // [N,N] float 0/1
    float* __restrict__ mean_out)            // [N,N]
{
    const int q = blockIdx.x * 256 + threadIdx.x;   // 0 .. 1024*513-1
    const int r = q / 513;
    const int c = q - r * 513;
    const int j = (r + c) & 1023;

    const float2 jr  = ((const float2*)junc)[r];
    const float2 jjc = ((const float2*)junc)[j];

    float acc = 0.0f;           // in u8 counts (x255)
    float mn  = __builtin_inff();

    #pragma unroll
    for (int s0 = 0; s0 < 64; s0 += 16) {
        float chv[16], cwv[16];
        unsigned int cv[16];
        #pragma unroll
        for (int u = 0; u < 16; ++u) {
            const int s = s0 + u;
            const float t  = sample_t(s);
            const float om = 1.0f - t;
            // Reference op order: ji*t + jj*(1-t), contraction-proof.
            float ch = __fadd_rn(__fmul_rn(jr.x, t), __fmul_rn(jjc.x, om));
            float cw = __fadd_rn(__fmul_rn(jr.y, t), __fmul_rn(jjc.y, om));
            ch = fminf(fmaxf(ch, 0.0f), 1023.0f);
            cw = fminf(fmaxf(cw, 0.0f), 1023.0f);
            chv[u] = ch;
            cwv[u] = cw;
            const int hfi = (int)ch;   // trunc == floor for non-negative
            const int wfi = (int)cw;
            cv[u] = packed[(hfi << 10) + wfi];
        }
        #pragma unroll
        for (int u = 0; u < 16; ++u) {
            const float ch = chv[u], cw = cwv[u];
            const float hf = floorf(ch), hc = ceilf(ch);
            const float wf = floorf(cw), wc = ceilf(cw);
            const float wh0 = hc - ch, wh1 = ch - hf;
            const float ww0 = wc - cw, ww1 = cw - wf;
            const unsigned int cc = cv[u];
            const float a00 = (float)(cc & 0xffu);
            const float a01 = (float)((cc >> 8) & 0xffu);
            const float a10 = (float)((cc >> 16) & 0xffu);
            const float a11 = (float)(cc >> 24);
            const float feat = a00 * (wh0 * ww0) + a01 * (wh0 * ww1)
                             + a10 * (wh1 * ww0) + a11 * (wh1 * ww1);
            acc += feat;
            mn = fminf(mn, feat);
        }
    }

    float mean = acc * (1.0f / (255.0f * 64.0f));
    const float mns = mn * (1.0f / 255.0f);

    // Conservative candidate test: exact detection implies u8 min/mean > RESCUE.
    bool det = false;
    if ((mns > RESCUE) && (mean > RESCUE) && (c != 0)) {
        float mn2;
        exact_pair(jr, jjc, heat, mean, mn2);
        det = (mean > DETECT) && (mn2 > DETECT);
    }

    const int p1 = (r << 10) + j;
    // nt: streaming outputs must not evict the L2-resident packed/heat arrays.
    __builtin_nontemporal_store(mean, mean_out + p1);
    __builtin_nontemporal_store(det ? 1.0f : 0.0f, line_out + p1);
}

// Fill complement band (d = (j-i) mod 1024 in [513,1023]) from the mirror cell:
// out[i][j] = out[j][i]. LDS-tiled 64x64 transpose; blocks fully outside the
// band exit before any loads.
__global__ __launch_bounds__(256) void mirror_kernel(
    float* __restrict__ line_out, float* __restrict__ mean_out)
{
    __shared__ float lm[64][65];
    __shared__ float mm[64][65];
    const int bi = blockIdx.x >> 4;      // dst tile row block
    const int bj = blockIdx.x & 15;      // dst tile col block

    // d over the tile = (64*(bj-bi) + delta) mod 1024, delta in [-63,63].
    // Entirely inside [0,512] (i.e. no band cells) iff D in [63,449].
    const int D = ((bj - bi) << 6) & 1023;
    if (D >= 63 && D <= 449) return;

    const int tx = threadIdx.x & 63;
    const int g  = threadIdx.x >> 6;     // 0..3

    #pragma unroll
    for (int k = 0; k < 16; ++k) {
        const int b = (g << 4) + k;
        const int src = ((bj << 6) + b) * 1024 + (bi << 6) + tx;
        lm[b][tx] = line_out[src];
        mm[b][tx] = mean_out[src];
    }
    __syncthreads();

    #pragma unroll
    for (int k = 0; k < 16; ++k) {
        const int a = (g << 4) + k;
        const int i = (bi << 6) + a;
        const int j = (bj << 6) + tx;
        const int d = (j - i) & 1023;
        if (d >= 513) {
            const int dst = i * 1024 + j;
            __builtin_nontemporal_store(lm[tx][a], line_out + dst);
            __builtin_nontemporal_store(mm[tx][a], mean_out + dst);
        }
    }
}

extern "C" void kernel_launch(void* const* d_in, const int* in_sizes, int n_in,
                              void* d_out, int out_size, void* d_ws, size_t ws_size,
                              hipStream_t stream) {
    const float* junc = (const float*)d_in[0];   // [1024,2] float32
    const float* heat = (const float*)d_in[1];   // [1024,1024] float32
    float* line_out = (float*)d_out;
    float* mean_out = line_out + NJ * NJ;

    unsigned int* packed = (unsigned int*)d_ws;  // 4 MB scratch
    pack_kernel<<<1024, 256, 0, stream>>>(heat, (uint4*)packed);

    const int total = NJ * 513;                  // 525,312 threads = 2052 blocks
    sold2_thread_kernel<<<total / 256, 256, 0, stream>>>(junc, heat, packed,
                                                         line_out, mean_out);

    mirror_kernel<<<256, 256, 0, stream>>>(line_out, mean_out);
}